// Round 8
// baseline (236.630 us; speedup 1.0000x reference)
//
#include <hip/hip_runtime.h>
#include <hip/hip_fp16.h>

// CommNet critic forward, fully fused: 1 workgroup = 2 batches (64 agent-rows).
// All GEMMs via v_mfma_f32_16x16x32_f16 (fp32 accumulate). B=2048,A=32,D=128,H=256.
// V9: 1024 threads (16 waves = 44% occupancy; runtime never co-schedules 2 blocks/CU,
//     so block size is the only occupancy lever) with every K-loop's live set sized
//     for the 64-VGPR budget that 1024-thread blocks always get:
//     - each wave owns ONE 16-col tile (nt = wave id)
//     - GRU1/GRU2 run as TWO row-half passes (one half = one batch):
//       GRU1 24 acc regs, GRU2 32 acc regs per pass -> no spill (V3 needed 64+, spilled)
//     - fobs accs kept in regs as GRU1's 'hold' (-16 scalar LDS reads/thread)
//     - clamp-free NaN-safe sigmoid/tanh (saves ~4 VALU x 192 calls/thread)

#define NB   2048
#define NA   32
#define DIN  128
#define HID  256
#define SA   264   // f16 row stride for activation LDS tiles (528B stride -> 4-bank stagger)
#define MROWS 64   // 2 batches x 32 agents

typedef _Float16 half8  __attribute__((ext_vector_type(8)));
typedef float    float4v __attribute__((ext_vector_type(4)));

// f16 weight-fragment arena layout in d_ws (element offsets)
#define ENC_OFF    0
#define FOBS_OFF   32768
#define WIH_OFF    98304
#define WHH_OFF    294912
#define PREP_TOTAL 491520   // f16 elements -> 983040 bytes needed in ws

// Pre-arrange weights into exact MFMA B-fragment order, f16:
// frag[((ks*NT + nt)*64 + lane)*8 + j] = W[nt*16 + lane%16][ks*32 + (lane/16)*8 + j]
__global__ void prep_weights(const float* __restrict__ encW, const float* __restrict__ fobsW,
                             const float* __restrict__ wih,  const float* __restrict__ whh,
                             _Float16* __restrict__ prep) {
    int F = blockIdx.x * 256 + threadIdx.x;
    if (F >= PREP_TOTAL) return;
    const float* src; int K, NT, local = F;
    if (F < FOBS_OFF)     { src = encW;  K = 128; NT = 16; }
    else if (F < WIH_OFF) { src = fobsW; K = 256; NT = 16; local = F - FOBS_OFF; }
    else if (F < WHH_OFF) { src = wih;   K = 256; NT = 48; local = F - WIH_OFF; }
    else                  { src = whh;   K = 256; NT = 48; local = F - WHH_OFF; }
    int j    = local & 7;
    int lane = (local >> 3) & 63;
    int t    = local >> 9;
    int nt   = t % NT;
    int ks   = t / NT;
    int col  = nt * 16 + (lane & 15);
    int k    = ks * 32 + ((lane >> 4) << 3) + j;
    prep[F] = (_Float16)src[col * K + k];
}

// NaN-safe, clamp-free: exp(+-inf) saturates cleanly through the rcp.
__device__ __forceinline__ float sigmoid_f(float x) {
    return 1.f / (1.f + __expf(-x));
}
__device__ __forceinline__ float tanh_f(float x) {
    return 1.f - 2.f / (__expf(2.f * x) + 1.f);
}

// Load one MFMA B-fragment (16 cols x 32 k) either from prepped arena or raw fp32.
__device__ __forceinline__ half8 ldB(const _Float16* __restrict__ prepm, int NT, int nt, int ks,
                                     const float* __restrict__ raw, int K, int use_prep, int lane) {
    if (use_prep)
        return *(const half8*)(prepm + (((ks * NT + nt) * 64 + lane) << 3));
    half8 b;
    int l16 = lane & 15, kq = (lane >> 4) << 3;
    #pragma unroll
    for (int j = 0; j < 8; j++)
        b[j] = (_Float16)raw[(nt * 16 + l16) * K + ks * 32 + kq + j];
    return b;
}

__global__ __launch_bounds__(1024) void commnet_fused(
    const float* __restrict__ obs, const _Float16* __restrict__ prep,
    const float* __restrict__ enc_b, const float* __restrict__ fobs_b,
    const float* __restrict__ b_ih, const float* __restrict__ b_hh,
    const float* __restrict__ dec_W, const float* __restrict__ dec_b,
    float* __restrict__ out,
    const float* __restrict__ encW, const float* __restrict__ fobsW,
    const float* __restrict__ wih, const float* __restrict__ whh,
    int use_prep)
{
    const int b    = blockIdx.x;       // block handles batches 2b, 2b+1 (rows 0..63)
    const int tid  = threadIdx.x;
    const int lane = tid & 63;
    const int nt   = tid >> 6;         // wave 0..15 -> col tile nt (cols 16nt..16nt+15)
    const int l16  = lane & 15;
    const int quad = lane >> 4;
    const int kq   = quad << 3;
    const int col  = nt * 16 + l16;    // this lane's output column (fixed all phases)

    __shared__ __align__(16) _Float16 sA[2][MROWS * SA];
    __shared__ __align__(16) float S[2][HID];   // per-batch column sums of h1
    __shared__ float Srow[MROWS];               // decoder row accumulators

    // ---- stage obs (fp32 global -> f16 LDS): 64 rows x 128, one half8 per thread
    {
        const float* obsb = obs + (size_t)b * MROWS * DIN;
        int r   = tid >> 4;            // 16 chunks per 128-wide row, 64 rows
        int off = (tid & 15) << 3;
        const float* src = obsb + r * DIN + off;
        float4v v0 = *(const float4v*)(src);
        float4v v1 = *(const float4v*)(src + 4);
        half8 hv;
        hv[0] = (_Float16)v0[0]; hv[1] = (_Float16)v0[1];
        hv[2] = (_Float16)v0[2]; hv[3] = (_Float16)v0[3];
        hv[4] = (_Float16)v1[0]; hv[5] = (_Float16)v1[1];
        hv[6] = (_Float16)v1[2]; hv[7] = (_Float16)v1[3];
        *(half8*)(&sA[0][r * SA + off]) = hv;
    }
    __syncthreads();

    // ---- encoder: e = relu(obs @ encW^T + enc_b) : T0 -> T1 (single pass, 16 accs)
    {
        float4v acc[4];
        float4v z = {0.f, 0.f, 0.f, 0.f};
        acc[0] = z; acc[1] = z; acc[2] = z; acc[3] = z;
        #pragma unroll
        for (int ks = 0; ks < 4; ks++) {
            int kbase = ks * 32 + kq;
            half8 Af[4];
            #pragma unroll
            for (int mt = 0; mt < 4; mt++)
                Af[mt] = *(const half8*)(&sA[0][(mt * 16 + l16) * SA + kbase]);
            half8 b0 = ldB(prep + ENC_OFF, 16, nt, ks, encW, DIN, use_prep, lane);
            #pragma unroll
            for (int mt = 0; mt < 4; mt++)
                acc[mt] = __builtin_amdgcn_mfma_f32_16x16x32_f16(Af[mt], b0, acc[mt], 0, 0, 0);
        }
        float bb = enc_b[col];
        #pragma unroll
        for (int mt = 0; mt < 4; mt++)
            #pragma unroll
            for (int r = 0; r < 4; r++) {
                int row = mt * 16 + quad * 4 + r;
                sA[1][row * SA + col] = (_Float16)fmaxf(acc[mt][r] + bb, 0.f);
            }
    }
    __syncthreads();

    // ---- fobs: h = e @ fobsW^T + fobs_b : T1 -> T0. Keep h (f32) in regs as GRU1's hold.
    float4v hacc[4];
    {
        float4v z = {0.f, 0.f, 0.f, 0.f};
        hacc[0] = z; hacc[1] = z; hacc[2] = z; hacc[3] = z;
        #pragma unroll 2
        for (int ks = 0; ks < 8; ks++) {
            int kbase = ks * 32 + kq;
            half8 Af[4];
            #pragma unroll
            for (int mt = 0; mt < 4; mt++)
                Af[mt] = *(const half8*)(&sA[1][(mt * 16 + l16) * SA + kbase]);
            half8 b0 = ldB(prep + FOBS_OFF, 16, nt, ks, fobsW, HID, use_prep, lane);
            #pragma unroll
            for (int mt = 0; mt < 4; mt++)
                hacc[mt] = __builtin_amdgcn_mfma_f32_16x16x32_f16(Af[mt], b0, hacc[mt], 0, 0, 0);
        }
        float bb = fobs_b[col];
        #pragma unroll
        for (int mt = 0; mt < 4; mt++)
            #pragma unroll
            for (int r = 0; r < 4; r++) {
                int row = mt * 16 + quad * 4 + r;
                float h = hacc[mt][r] + bb;
                hacc[mt][r] = h;                       // keep f32 h as GRU1 hold
                sA[0][row * SA + col] = (_Float16)h;
            }
    }
    __syncthreads();

    // ---- GRU1 fused (x=0 so gi = b_ih). A = T0 (h). Two row-half passes (= batches).
    #pragma unroll 1
    for (int half = 0; half < 2; half++) {
        const int rb = half * 32;
        float4v aR[2], aZ[2], aN[2];
        float4v z = {0.f, 0.f, 0.f, 0.f};
        aR[0] = z; aR[1] = z; aZ[0] = z; aZ[1] = z; aN[0] = z; aN[1] = z;
        #pragma unroll 2
        for (int ks = 0; ks < 8; ks++) {
            const int kbase = ks * 32 + kq;
            half8 A0 = *(const half8*)(&sA[0][(rb + l16) * SA + kbase]);
            half8 A1 = *(const half8*)(&sA[0][(rb + 16 + l16) * SA + kbase]);
            half8 bR = ldB(prep + WHH_OFF, 48,  0 + nt, ks, whh, HID, use_prep, lane);
            half8 bZ = ldB(prep + WHH_OFF, 48, 16 + nt, ks, whh, HID, use_prep, lane);
            half8 bN = ldB(prep + WHH_OFF, 48, 32 + nt, ks, whh, HID, use_prep, lane);
            aR[0] = __builtin_amdgcn_mfma_f32_16x16x32_f16(A0, bR, aR[0], 0, 0, 0);
            aR[1] = __builtin_amdgcn_mfma_f32_16x16x32_f16(A1, bR, aR[1], 0, 0, 0);
            aZ[0] = __builtin_amdgcn_mfma_f32_16x16x32_f16(A0, bZ, aZ[0], 0, 0, 0);
            aZ[1] = __builtin_amdgcn_mfma_f32_16x16x32_f16(A1, bZ, aZ[1], 0, 0, 0);
            aN[0] = __builtin_amdgcn_mfma_f32_16x16x32_f16(A0, bN, aN[0], 0, 0, 0);
            aN[1] = __builtin_amdgcn_mfma_f32_16x16x32_f16(A1, bN, aN[1], 0, 0, 0);
        }
        float biR = b_ih[col],       bhR = b_hh[col];
        float biZ = b_ih[256 + col], bhZ = b_hh[256 + col];
        float biN = b_ih[512 + col], bhN = b_hh[512 + col];
        float psum = 0.f;
        #pragma unroll
        for (int mt = 0; mt < 2; mt++)
            #pragma unroll
            for (int r = 0; r < 4; r++) {
                int row = rb + mt * 16 + quad * 4 + r;
                float rg = sigmoid_f(biR + aR[mt][r] + bhR);
                float zg = sigmoid_f(biZ + aZ[mt][r] + bhZ);
                float ng = tanh_f(biN + rg * (aN[mt][r] + bhN));
                float hold = hacc[half * 2 + mt][r];   // f32 h from regs, no LDS read
                float h1 = (1.f - zg) * ng + zg * hold;
                sA[1][row * SA + col] = (_Float16)h1;  // h1 -> T1
                psum += h1;
            }
        // column sum over this half's 32 rows (all in batch `half`)
        psum += __shfl_xor(psum, 16);
        psum += __shfl_xor(psum, 32);
        if (lane < 16) S[half][nt * 16 + lane] = psum;
    }
    __syncthreads();

    // ---- comm: c = (colsum - h1)/32 : T1 -> T0 (per-batch colsum), vectorized half8
    {
        #pragma unroll
        for (int it = 0; it < 2; it++) {
            int i  = tid + it * 1024;       // 2048 chunks total
            int r  = i >> 5;                // row 0..63
            int c8 = (i & 31) << 3;
            const float* Sp = &S[r >> 5][0];
            half8 hv = *(const half8*)(&sA[1][r * SA + c8]);
            float4v t0 = *(const float4v*)(Sp + c8);
            float4v t1 = *(const float4v*)(Sp + c8 + 4);
            half8 cv;
            cv[0] = (_Float16)((t0[0] - (float)hv[0]) * (1.f / 32.f));
            cv[1] = (_Float16)((t0[1] - (float)hv[1]) * (1.f / 32.f));
            cv[2] = (_Float16)((t0[2] - (float)hv[2]) * (1.f / 32.f));
            cv[3] = (_Float16)((t0[3] - (float)hv[3]) * (1.f / 32.f));
            cv[4] = (_Float16)((t1[0] - (float)hv[4]) * (1.f / 32.f));
            cv[5] = (_Float16)((t1[1] - (float)hv[5]) * (1.f / 32.f));
            cv[6] = (_Float16)((t1[2] - (float)hv[6]) * (1.f / 32.f));
            cv[7] = (_Float16)((t1[3] - (float)hv[7]) * (1.f / 32.f));
            *(half8*)(&sA[0][r * SA + c8]) = cv;
        }
        if (tid < MROWS) Srow[tid] = 0.f;   // decoder row accumulators
    }
    __syncthreads();

    // ---- GRU2 fused: gi from c (T0) @ W_ih, gh from h1 (T1) @ W_hh.
    // Two row-half passes; r,z share accumulators; 32 acc regs per pass.
    #pragma unroll 1
    for (int half = 0; half < 2; half++) {
        const int rb = half * 32;
        float4v aR[2], aZ[2], aNi[2], aNh[2];
        float4v z = {0.f, 0.f, 0.f, 0.f};
        aR[0] = z; aR[1] = z; aZ[0] = z; aZ[1] = z;
        aNi[0] = z; aNi[1] = z; aNh[0] = z; aNh[1] = z;
        #pragma unroll 1
        for (int ks = 0; ks < 8; ks++) {
            const int kbase = ks * 32 + kq;
            // gi side: A = c
            {
                half8 C0 = *(const half8*)(&sA[0][(rb + l16) * SA + kbase]);
                half8 C1 = *(const half8*)(&sA[0][(rb + 16 + l16) * SA + kbase]);
                half8 bR = ldB(prep + WIH_OFF, 48,  0 + nt, ks, wih, HID, use_prep, lane);
                half8 bZ = ldB(prep + WIH_OFF, 48, 16 + nt, ks, wih, HID, use_prep, lane);
                half8 bN = ldB(prep + WIH_OFF, 48, 32 + nt, ks, wih, HID, use_prep, lane);
                aR[0]  = __builtin_amdgcn_mfma_f32_16x16x32_f16(C0, bR, aR[0], 0, 0, 0);
                aR[1]  = __builtin_amdgcn_mfma_f32_16x16x32_f16(C1, bR, aR[1], 0, 0, 0);
                aZ[0]  = __builtin_amdgcn_mfma_f32_16x16x32_f16(C0, bZ, aZ[0], 0, 0, 0);
                aZ[1]  = __builtin_amdgcn_mfma_f32_16x16x32_f16(C1, bZ, aZ[1], 0, 0, 0);
                aNi[0] = __builtin_amdgcn_mfma_f32_16x16x32_f16(C0, bN, aNi[0], 0, 0, 0);
                aNi[1] = __builtin_amdgcn_mfma_f32_16x16x32_f16(C1, bN, aNi[1], 0, 0, 0);
            }
            // gh side: A = h1
            {
                half8 H0 = *(const half8*)(&sA[1][(rb + l16) * SA + kbase]);
                half8 H1 = *(const half8*)(&sA[1][(rb + 16 + l16) * SA + kbase]);
                half8 bR = ldB(prep + WHH_OFF, 48,  0 + nt, ks, whh, HID, use_prep, lane);
                half8 bZ = ldB(prep + WHH_OFF, 48, 16 + nt, ks, whh, HID, use_prep, lane);
                half8 bN = ldB(prep + WHH_OFF, 48, 32 + nt, ks, whh, HID, use_prep, lane);
                aR[0]  = __builtin_amdgcn_mfma_f32_16x16x32_f16(H0, bR, aR[0], 0, 0, 0);
                aR[1]  = __builtin_amdgcn_mfma_f32_16x16x32_f16(H1, bR, aR[1], 0, 0, 0);
                aZ[0]  = __builtin_amdgcn_mfma_f32_16x16x32_f16(H0, bZ, aZ[0], 0, 0, 0);
                aZ[1]  = __builtin_amdgcn_mfma_f32_16x16x32_f16(H1, bZ, aZ[1], 0, 0, 0);
                aNh[0] = __builtin_amdgcn_mfma_f32_16x16x32_f16(H0, bN, aNh[0], 0, 0, 0);
                aNh[1] = __builtin_amdgcn_mfma_f32_16x16x32_f16(H1, bN, aNh[1], 0, 0, 0);
            }
        }

        // epilogue + decoder fold for this half
        float biR = b_ih[col],       bhR = b_hh[col];
        float biZ = b_ih[256 + col], bhZ = b_hh[256 + col];
        float biN = b_ih[512 + col], bhN = b_hh[512 + col];
        float dw  = dec_W[col];
        float p[2][4];
        #pragma unroll
        for (int mt = 0; mt < 2; mt++)
            #pragma unroll
            for (int r = 0; r < 4; r++) {
                int row = rb + mt * 16 + quad * 4 + r;
                float rg = sigmoid_f(aR[mt][r] + biR + bhR);
                float zg = sigmoid_f(aZ[mt][r] + biZ + bhZ);
                float ng = tanh_f((aNi[mt][r] + biN) + rg * (aNh[mt][r] + bhN));
                float h1v = (float)sA[1][row * SA + col];
                float h2 = (1.f - zg) * ng + zg * h1v;
                p[mt][r] = h2 * dw;
            }
        #pragma unroll
        for (int m = 1; m <= 8; m <<= 1) {
            #pragma unroll
            for (int mt = 0; mt < 2; mt++)
                #pragma unroll
                for (int r = 0; r < 4; r++)
                    p[mt][r] += __shfl_xor(p[mt][r], m);
        }
        if (l16 == 0) {
            #pragma unroll
            for (int mt = 0; mt < 2; mt++)
                #pragma unroll
                for (int r = 0; r < 4; r++)
                    atomicAdd(&Srow[rb + mt * 16 + quad * 4 + r], p[mt][r]);
        }
    }
    __syncthreads();
    if (tid < MROWS) out[(size_t)b * MROWS + tid] = Srow[tid] + dec_b[0];
}

extern "C" void kernel_launch(void* const* d_in, const int* in_sizes, int n_in,
                              void* d_out, int out_size, void* d_ws, size_t ws_size,
                              hipStream_t stream) {
    const float* obs   = (const float*)d_in[0];
    // d_in[1] (act) is unused by the reference
    const float* encW  = (const float*)d_in[2];
    const float* encb  = (const float*)d_in[3];
    const float* fobsW = (const float*)d_in[4];
    const float* fobsb = (const float*)d_in[5];
    const float* wih   = (const float*)d_in[6];
    const float* bih   = (const float*)d_in[7];
    const float* whh   = (const float*)d_in[8];
    const float* bhh   = (const float*)d_in[9];
    const float* decW  = (const float*)d_in[10];
    const float* decb  = (const float*)d_in[11];
    float* out = (float*)d_out;

    _Float16* prep = (_Float16*)d_ws;
    int use_prep = (ws_size >= (size_t)PREP_TOTAL * sizeof(_Float16)) ? 1 : 0;
    if (use_prep) {
        prep_weights<<<(PREP_TOTAL + 255) / 256, 256, 0, stream>>>(encW, fobsW, wih, whh, prep);
    }
    commnet_fused<<<NB / 2, 1024, 0, stream>>>(obs, prep, encb, fobsb, bih, bhh, decW, decb, out,
                                               encW, fobsW, wih, whh, use_prep);
}